// Round 7
// baseline (465.799 us; speedup 1.0000x reference)
//
#include <hip/hip_runtime.h>
#include <math.h>

// B=8, Cin=256, H=W=128, RC=128, NC=12, HD=64, NL=3, E=132
#define BNS_F 0.9999950000374998f

typedef short short8 __attribute__((ext_vector_type(8)));   // 8 bf16 (4 VGPRs)
typedef float f32x4 __attribute__((ext_vector_type(4)));    // MFMA C/D frag

__device__ __forceinline__ unsigned short f2bf(float f) {
    unsigned u = __builtin_bit_cast(unsigned, f);
    unsigned r = (u + 0x7fffu + ((u >> 16) & 1u)) >> 16;   // RNE
    return (unsigned short)r;
}
__device__ __forceinline__ float bf2f(unsigned short h) {
    unsigned u = ((unsigned)h) << 16;
    return __builtin_bit_cast(float, u);
}

// =====================================================================
// convert features fp32 [b][ic][px] -> bf16 grouped [b][ic/8][px][8ic]
// No LDS: lane reads 8 px-coalesced floats (one per ic in group),
// packs 8 bf16, writes one 16B uint4 -> 1KB/wave-instr coalesced.
// grid: 8 b x 32 icg x 64 px-chunks = 16384 blocks, 256 thr.
// =====================================================================
__global__ __launch_bounds__(256) void convert_feat(
    const float* __restrict__ feat, unsigned short* __restrict__ Fbt)
{
    int bid = blockIdx.x;
    int pxc = bid & 63;
    int icg = (bid >> 6) & 31;
    int b   = bid >> 11;
    int px  = pxc * 256 + threadIdx.x;

    const float* src = feat + ((size_t)(b * 256 + icg * 8)) * 16384 + px;
    unsigned v[4];
    #pragma unroll
    for (int i = 0; i < 4; ++i) {
        unsigned lo = f2bf(src[(size_t)(2 * i)     * 16384]);
        unsigned hi = f2bf(src[(size_t)(2 * i + 1) * 16384]);
        v[i] = lo | (hi << 16);
    }
    uint4 o; o.x = v[0]; o.y = v[1]; o.z = v[2]; o.w = v[3];
    *(uint4*)(Fbt + (((size_t)(b * 32 + icg) * 16384) + px) * 8) = o;
}

// =====================================================================
// reorg W_rpn[oc][ic][tap] fp32 -> Wr[tap][oc][ic] bf16
// =====================================================================
__global__ __launch_bounds__(256) void reorg_w(
    const float* __restrict__ Wrpn, unsigned short* __restrict__ Wr)
{
    int oc = blockIdx.x;            // 128
    int ic = threadIdx.x;           // 256
    const float* src = Wrpn + ((size_t)oc * 256 + ic) * 9;
    #pragma unroll
    for (int tap = 0; tap < 9; ++tap)
        Wr[((size_t)tap * 128 + oc) * 256 + ic] = f2bf(src[tap]);
}

// =====================================================================
// masks = (maxpool3x3(seg) > 0.5), mask_sum[b,c]
// =====================================================================
__global__ __launch_bounds__(128) void masks_kernel(
    const float* __restrict__ seg, float* __restrict__ masks,
    float* __restrict__ mask_sum)
{
    int bid = blockIdx.x;
    int h = bid & 127;
    int c = (bid >> 7) % 12;
    int b = bid / (128 * 12);
    int px = threadIdx.x;

    const float* s = seg + ((size_t)(b * 12 + c) * 128) * 128;
    float m = -INFINITY;
    #pragma unroll
    for (int dy = -1; dy <= 1; ++dy) {
        int y = h + dy;
        if (y < 0 || y > 127) continue;
        #pragma unroll
        for (int dx = -1; dx <= 1; ++dx) {
            int x = px + dx;
            if (x < 0 || x > 127) continue;
            m = fmaxf(m, s[y * 128 + x]);
        }
    }
    float v = (m > 0.5f) ? 1.0f : 0.0f;
    masks[((size_t)(b * 12 + c) * 128 + h) * 128 + px] = v;

    float cnt = v;
    #pragma unroll
    for (int off = 1; off < 64; off <<= 1) cnt += __shfl_xor(cnt, off, 64);
    if ((threadIdx.x & 63) == 0) atomicAdd(&mask_sum[b * 12 + c], cnt);
}

// =====================================================================
// MFMA implicit-GEMM conv + fused 1x1 + masked sums.  v5: 4 blocks/CU.
// Single 24.96KB LDS staging buffer + REGISTER staging (T14):
//   per chunk s: [issue global loads for s+1 into st0..st3]
//                [compute chunk s: A-loads + ds_read + 72 MFMA/wave]
//                __syncthreads()  (everyone done reading buf)
//                [ds_write st -> buf] __syncthreads()
// HBM/L2 latency of the staged loads hides under the MFMA phase and
// under 3 other co-resident blocks (grid 1024 = 4 x 256 CUs exactly).
// =====================================================================
#define SWZ(col) (((col) >> 1) & 3)
#define CHUNK_STRIDE (4 * 16384 * 8)   // +32 ic = +4 icg, in ushorts

__global__ __launch_bounds__(512) void conv_node_kernel(
    const unsigned short* __restrict__ Fbt, const unsigned short* __restrict__ Wr,
    const float* __restrict__ brpn, const float* __restrict__ Wnode,
    const float* __restrict__ bnode, const float* __restrict__ masks,
    const float* __restrict__ zero16, float* __restrict__ ms_rep)
{
    __shared__ __align__(16) unsigned char lds[33280]; // staging 24960; epilogue 33280

    // XCD swizzle: 1024 wgs, XCD x gets logical blocks [x*128, x*128+128) = batch x
    int wg = blockIdx.x;
    int bid = (wg & 7) * 128 + (wg >> 3);
    int h = bid & 127, b = bid >> 7;

    int t = threadIdx.x;
    int lane = t & 63;
    int wv = __builtin_amdgcn_readfirstlane(t >> 6);  // 0..7 wave-uniform
    int mg = wv >> 1;        // oc0 = mg*32
    int ng = wv & 1;         // px0 = ng*64
    int kg = lane >> 4;      // 0..3
    int ln15 = lane & 15;

    f32x4 acc[2][4];
    #pragma unroll
    for (int i = 0; i < 2; ++i)
        #pragma unroll
        for (int j = 0; j < 4; ++j) acc[i][j] = (f32x4){0.f, 0.f, 0.f, 0.f};

    // ---- per-thread staging descriptors (4 rounds: 3x512 + 24 extras) ----
    // chunk c -> (slot sp = c&3, cr = c>>2, col = cr%130, row = cr/130)
    // source: Fbt[((b*32 + ic0/8 + sl)*16384 + y*128 + x)*8], halo -> zero16
    const unsigned short* p[4];
    size_t inc[4];
    unsigned woff[4];
    bool act3 = (t < 24);
    #pragma unroll
    for (int r = 0; r < 4; ++r) {
        int c = (r < 3) ? (r * 512 + t) : (1536 + t);
        bool act = (r < 3) || act3;
        int sp = c & 3, cr = c >> 2;
        int col = cr % 130, row = cr / 130;
        int sl = (sp - SWZ(col)) & 3;
        int y = h - 1 + row;
        int x = col - 1;
        bool in = ((unsigned)y < 128u) && ((unsigned)x < 128u) && act;
        p[r]   = in ? (Fbt + (((size_t)(b * 32 + sl) * 16384) + y * 128 + x) * 8)
                    : (const unsigned short*)zero16;
        inc[r] = in ? (size_t)CHUNK_STRIDE : 0;
        woff[r] = (unsigned)c * 16;
    }

    // prologue: stage chunk 0 through registers
    {
        uint4 s0 = *(const uint4*)p[0];
        uint4 s1 = *(const uint4*)p[1];
        uint4 s2 = *(const uint4*)p[2];
        uint4 s3 = act3 ? *(const uint4*)p[3] : (uint4){0, 0, 0, 0};
        p[0] += inc[0]; p[1] += inc[1]; p[2] += inc[2]; p[3] += inc[3];
        *(uint4*)(lds + woff[0]) = s0;
        *(uint4*)(lds + woff[1]) = s1;
        *(uint4*)(lds + woff[2]) = s2;
        if (act3) *(uint4*)(lds + woff[3]) = s3;
    }
    __syncthreads();

    for (int s = 0; s < 8; ++s) {
        int ic0 = s * 32;

        // ---- issue next-chunk loads into registers (latency hides below) ----
        uint4 st0, st1, st2, st3;
        bool pre = (s < 7);
        if (pre) {
            st0 = *(const uint4*)p[0];
            st1 = *(const uint4*)p[1];
            st2 = *(const uint4*)p[2];
            st3 = act3 ? *(const uint4*)p[3] : (uint4){0, 0, 0, 0};
            p[0] += inc[0]; p[1] += inc[1]; p[2] += inc[2]; p[3] += inc[3];
        }

        // ---- compute chunk s ----
        #pragma unroll
        for (int dy = 0; dy < 3; ++dy) {
            #pragma unroll
            for (int dxi = 0; dxi < 3; ++dxi) {
                int tap = dy * 3 + dxi;
                const unsigned short* wp =
                    Wr + ((size_t)(tap * 128 + mg * 32 + ln15) * 256 + ic0 + kg * 8);
                short8 a0 = *(const short8*)wp;
                short8 a1 = *(const short8*)(wp + (size_t)16 * 256);
                short8 bf[4];
                #pragma unroll
                for (int nt = 0; nt < 4; ++nt) {
                    int col = ng * 64 + nt * 16 + ln15 + dxi;
                    unsigned off =
                        (unsigned)((dy * 130 + col) * 4 + ((kg + SWZ(col)) & 3)) * 16;
                    bf[nt] = *(const short8*)(lds + off);
                }
                #pragma unroll
                for (int nt = 0; nt < 4; ++nt) {
                    acc[0][nt] = __builtin_amdgcn_mfma_f32_16x16x32_bf16(
                        a0, bf[nt], acc[0][nt], 0, 0, 0);
                    acc[1][nt] = __builtin_amdgcn_mfma_f32_16x16x32_bf16(
                        a1, bf[nt], acc[1][nt], 0, 0, 0);
                }
            }
        }

        __syncthreads();                 // all waves done READING buf
        if (pre) {
            *(uint4*)(lds + woff[0]) = st0;
            *(uint4*)(lds + woff[1]) = st1;
            *(uint4*)(lds + woff[2]) = st2;
            if (act3) *(uint4*)(lds + woff[3]) = st3;
            __syncthreads();             // buf holds chunk s+1
        }
    }

    // ---- epilogue: refined (bias/BNS/ReLU) -> LDS bf16 [128 oc][stride 130] ----
    unsigned short* refined = (unsigned short*)lds;
    #pragma unroll
    for (int mt = 0; mt < 2; ++mt) {
        #pragma unroll
        for (int nt = 0; nt < 4; ++nt) {
            int px = ng * 64 + nt * 16 + ln15;
            #pragma unroll
            for (int r = 0; r < 4; ++r) {
                int oc = mg * 32 + mt * 16 + kg * 4 + r;   // D: row=(lane>>4)*4+r
                float v = fmaxf((acc[mt][nt][r] + brpn[oc]) * BNS_F, 0.f);
                refined[oc * 130 + px] = f2bf(v);
            }
        }
    }
    __syncthreads();

    // ---- phase 2: z = relu((W_node @ refined + b)*BNS); wave -> 8 dims ----
    float z0[8], z1[8];
    #pragma unroll
    for (int j = 0; j < 8; ++j) { z0[j] = 0.f; z1[j] = 0.f; }
    const float* wn = Wnode + (size_t)wv * 8 * 128;
    for (int k = 0; k < 128; ++k) {
        float r0 = bf2f(refined[k * 130 + lane]);
        float r1 = bf2f(refined[k * 130 + 64 + lane]);
        #pragma unroll
        for (int j = 0; j < 8; ++j) {
            float w = wn[j * 128 + k];
            z0[j] = fmaf(w, r0, z0[j]);
            z1[j] = fmaf(w, r1, z1[j]);
        }
    }
    #pragma unroll
    for (int j = 0; j < 8; ++j) {
        float bb = bnode[wv * 8 + j];
        z0[j] = fmaxf((z0[j] + bb) * BNS_F, 0.f);
        z1[j] = fmaxf((z1[j] + bb) * BNS_F, 0.f);
    }

    // ---- masked accumulation into replica rep = bid&7 ----
    int rep = bid & 7;
    const float* mrow = masks + ((size_t)b * 12 * 128 + h) * 128;
    float* msb = ms_rep + ((size_t)(rep * 8 + b) * 12) * 64 + wv * 8;
    for (int c = 0; c < 12; ++c) {
        float m0 = mrow[(size_t)c * 16384 + lane];
        float m1 = mrow[(size_t)c * 16384 + 64 + lane];
        #pragma unroll
        for (int j = 0; j < 8; ++j) {
            float v = fmaf(z0[j], m0, z1[j] * m1);
            #pragma unroll
            for (int off2 = 1; off2 < 64; off2 <<= 1) v += __shfl_xor(v, off2, 64);
            if (lane == 0) atomicAdd(&msb[c * 64 + j], v);
        }
    }
}

// =====================================================================
// edge MLP: 264 blocks = 8 b x 33 edge-groups; wave = one edge
// =====================================================================
__global__ __launch_bounds__(256) void edge_kernel(
    const float* __restrict__ ms_rep, const float* __restrict__ mask_sum,
    const float* __restrict__ We1, const float* __restrict__ be1,
    const float* __restrict__ We2, const float* __restrict__ be2,
    float* __restrict__ ea_g)
{
    int gb = blockIdx.x;
    int b = gb / 33, eg = gb % 33;
    int wv = threadIdx.x >> 6, d = threadIdx.x & 63;
    int e = eg * 4 + wv;                    // 0..131
    int src = e / 11, jj = e % 11;
    int dst = jj + (jj >= src ? 1 : 0);

    float mssrc = 0.f, msdst = 0.f;
    #pragma unroll
    for (int rep = 0; rep < 8; ++rep) {
        mssrc += ms_rep[((size_t)(rep * 8 + b) * 12 + src) * 64 + d];
        msdst += ms_rep[((size_t)(rep * 8 + b) * 12 + dst) * 64 + d];
    }
    float cs = mask_sum[b * 12 + src], cd = mask_sum[b * 12 + dst];
    float nsrc = mssrc / (cs + 1e-6f);
    float ndst = msdst / (cd + 1e-6f);

    float hv = be1[d];
    for (int k = 0; k < 64; ++k) hv = fmaf(__shfl(nsrc, k, 64), We1[k * 64 + d], hv);
    for (int k = 0; k < 64; ++k) hv = fmaf(__shfl(ndst, k, 64), We1[(64 + k) * 64 + d], hv);
    hv = fmaxf(hv, 0.f);
    float av = be2[d];
    for (int k = 0; k < 64; ++k) av = fmaf(__shfl(hv, k, 64), We2[k * 64 + d], av);

    float valid = ((cs > 0.f) ? 1.f : 0.f) * ((cd > 0.f) ? 1.f : 0.f);
    ea_g[((size_t)b * 132 + e) * 64 + d] = av * valid;
}

// =====================================================================
// graph: node_feats -> 3-layer GNN -> xs = x_final @ W_sp  (8 blocks)
// =====================================================================
__global__ __launch_bounds__(256) void graph_kernel(
    const float* __restrict__ ms_rep, const float* __restrict__ mask_sum,
    const float* __restrict__ ea_g,
    const float* __restrict__ Wg, const float* __restrict__ bg,
    const float* __restrict__ lng, const float* __restrict__ lnb,
    const float* __restrict__ glob, const float* __restrict__ Wsp,
    float* __restrict__ xs_out)
{
    __shared__ float nf[12 * 64];
    __shared__ float x [12 * 64];
    __shared__ float xw[12 * 64];
    __shared__ float ea[132 * 64];
    __shared__ float presence[12];

    int b = blockIdx.x;
    int t = threadIdx.x;

    for (int i = t; i < 768; i += 256) {
        int c = i >> 6, d = i & 63;
        float ms = 0.f;
        #pragma unroll
        for (int rep = 0; rep < 8; ++rep)
            ms += ms_rep[((size_t)(rep * 8 + b) * 12 + c) * 64 + d];
        nf[i] = ms / (mask_sum[b * 12 + c] + 1e-6f);
    }
    for (int i = t; i < 132 * 64; i += 256) ea[i] = ea_g[(size_t)b * 8448 + i];
    __syncthreads();

    for (int i = t; i < 768; i += 256) {
        int c = i >> 6;
        float v = nf[i];
        #pragma unroll
        for (int off = 1; off < 64; off <<= 1) v += __shfl_xor(v, off, 64);
        if ((i & 63) == 0) presence[c] = (v != 0.f) ? 1.f : 0.f;
        x[i] = nf[i];
    }
    __syncthreads();

    for (int l = 0; l < 3; ++l) {
        const float* wg = Wg + l * 4096;
        for (int i = t; i < 768; i += 256) {
            int c = i >> 6, d = i & 63;
            float v = 0.f;
            for (int k = 0; k < 64; ++k) v = fmaf(x[c * 64 + k], wg[k * 64 + d], v);
            xw[i] = v;
        }
        __syncthreads();
        for (int i = t; i < 768; i += 256) {
            int j = i >> 6, d = i & 63;
            float agg = bg[l * 64 + d];
            #pragma unroll
            for (int src2 = 0; src2 < 12; ++src2) {
                if (src2 == j) continue;
                int jj2 = j - (j > src2 ? 1 : 0);
                int e = src2 * 11 + jj2;
                agg = fmaf(xw[src2 * 64 + d], ea[e * 64 + d], agg);
            }
            float xr = fmaxf(agg, 0.f);
            float s = xr;
            #pragma unroll
            for (int off = 1; off < 64; off <<= 1) s += __shfl_xor(s, off, 64);
            float mu = s * (1.f / 64.f);
            float df = xr - mu;
            float s2 = df * df;
            #pragma unroll
            for (int off = 1; off < 64; off <<= 1) s2 += __shfl_xor(s2, off, 64);
            float var = s2 * (1.f / 64.f);
            float normed = df * (1.0f / sqrtf(var + 1e-5f)) * lng[l * 64 + d]
                           + lnb[l * 64 + d];
            nf[i] = (l > 0) ? (normed + x[i]) : normed;
        }
        __syncthreads();
        for (int i = t; i < 768; i += 256) x[i] = nf[i];
        __syncthreads();
    }

    for (int i = t; i < 768; i += 256) {
        int c = i >> 6;
        float p = presence[c];
        x[i] = x[i] * p + glob[c * 64 + (i & 63)] * (1.f - p);
    }
    __syncthreads();

    for (int i = t; i < 12 * 128; i += 256) {
        int c = i >> 7, o = i & 127;
        float v = 0.f;
        for (int k = 0; k < 64; ++k) v = fmaf(x[c * 64 + k], Wsp[k * 128 + o], v);
        xs_out[b * 1536 + i] = v;
    }
}

// =====================================================================
// out[b,o,h,w] = relu((sum_c xs[b,c,o]*mask[b,c,h,w] + b_sp[o])*BNS)
// =====================================================================
__global__ __launch_bounds__(256) void out_kernel(
    const float* __restrict__ xs, const float* __restrict__ masks,
    const float* __restrict__ bsp, float* __restrict__ out)
{
    __shared__ float xsl[12 * 128];
    __shared__ float ml[12 * 128];
    int bid = blockIdx.x;
    int h = bid & 127;
    int b = bid >> 7;
    int t = threadIdx.x;

    for (int i = t; i < 1536; i += 256) xsl[i] = xs[b * 1536 + i];
    for (int i = t; i < 1536; i += 256) {
        int c = i >> 7, px = i & 127;
        ml[i] = masks[((size_t)(b * 12 + c) * 128 + h) * 128 + px];
    }
    __syncthreads();

    int px = t & 127;
    int og = t >> 7;
    float m[12];
    #pragma unroll
    for (int c = 0; c < 12; ++c) m[c] = ml[c * 128 + px];

    float* ob = out + ((size_t)b * 128 * 128 + h) * 128 + px;
    for (int i = 0; i < 64; ++i) {
        int o = og * 64 + i;
        float s = 0.f;
        #pragma unroll
        for (int c = 0; c < 12; ++c) s = fmaf(xsl[c * 128 + o], m[c], s);
        ob[(size_t)o * 16384] = fmaxf((s + bsp[o]) * BNS_F, 0.f);
    }
}

// =====================================================================
extern "C" void kernel_launch(void* const* d_in, const int* in_sizes, int n_in,
                              void* d_out, int out_size, void* d_ws, size_t ws_size,
                              hipStream_t stream)
{
    const float* feat  = (const float*)d_in[0];
    const float* seg   = (const float*)d_in[1];
    const float* Wrpn  = (const float*)d_in[2];
    const float* brpn  = (const float*)d_in[3];
    const float* Wnode = (const float*)d_in[4];
    const float* bnode = (const float*)d_in[5];
    const float* We1   = (const float*)d_in[6];
    const float* be1   = (const float*)d_in[7];
    const float* We2   = (const float*)d_in[8];
    const float* be2   = (const float*)d_in[9];
    const float* Wg    = (const float*)d_in[10];
    const float* bg    = (const float*)d_in[11];
    const float* lng   = (const float*)d_in[12];
    const float* lnb   = (const float*)d_in[13];
    const float* glob  = (const float*)d_in[14];
    const float* Wsp   = (const float*)d_in[15];
    const float* bsp   = (const float*)d_in[16];
    float* out = (float*)d_out;

    // Fbt (bf16 features, grouped pixel-major) lives in d_out (67.1 MB);
    // fully consumed by conv before out_kernel overwrites it.
    unsigned short* Fbt = (unsigned short*)d_out;

    // workspace (floats):
    float* masks    = (float*)d_ws;              // 1,572,864
    float* ms_rep   = masks + 1572864;           // 8*8*12*64 = 49,152
    float* mask_sum = ms_rep + 49152;            // 96
    float* zero16   = mask_sum + 96;             // 8 (16B zero stub)
    float* xs       = zero16 + 8;                // 12,288
    float* ea_g     = xs + 12288;                // 8*132*64 = 67,584
    unsigned short* Wr = (unsigned short*)(ea_g + 67584);  // 294,912 bf16

    hipMemsetAsync(ms_rep, 0, (49152 + 96 + 8) * sizeof(float), stream);

    convert_feat<<<16384, 256, 0, stream>>>(feat, Fbt);
    reorg_w<<<128, 256, 0, stream>>>(Wrpn, Wr);
    masks_kernel<<<8 * 12 * 128, 128, 0, stream>>>(seg, masks, mask_sum);
    conv_node_kernel<<<1024, 512, 0, stream>>>(Fbt, Wr, brpn, Wnode, bnode,
                                               masks, zero16, ms_rep);
    edge_kernel<<<264, 256, 0, stream>>>(ms_rep, mask_sum, We1, be1, We2, be2, ea_g);
    graph_kernel<<<8, 256, 0, stream>>>(ms_rep, mask_sum, ea_g,
                                        Wg, bg, lng, lnb, glob, Wsp, xs);
    out_kernel<<<1024, 256, 0, stream>>>(xs, masks, bsp, out);
}